// Round 1
// baseline (538.507 us; speedup 1.0000x reference)
//
#include <hip/hip_runtime.h>

// LinearAttention: out[b,h,l,v] = rq[l]*rk[l]*V[l,v] / (rq[l]*cs[l] + EPS)
//   rq = rowsum(elu(Q)+1), rk = rowsum(elu(K)+1), cs = colsum(elu(K)+1)
// B=H=8 -> 64 (b,h) tiles, L=DK=1024, DV=64, fp32 in/out. Memory-bound:
// ideal traffic 544 MB => ~86 us at 6.3 TB/s.

#define EPS 1e-6f

constexpr int L   = 1024;
constexpr int DK  = 1024;
constexpr int DV  = 64;
constexpr int NBH = 64;            // B*H
constexpr int ROWS_PER_BLOCK = 64; // rows of one (b,h) tile per block

__device__ __forceinline__ float elup(float x) {
    // elu(x)+1 = x+1 (x>0), exp(x) (x<=0)
    return x > 0.0f ? x + 1.0f : __expf(x);
}

// Pass 1: stream Q,K once; produce rowsumQ/rowsumK per row and colsum(Kp)
// per (b,h). 256 threads = 4 waves; each wave owns rows wave, wave+4, ...
// Each lane holds 16 column partials in registers (cols i*256+lane*4+j).
__global__ __launch_bounds__(256) void reduce_kernel(
    const float* __restrict__ Q, const float* __restrict__ K,
    float* __restrict__ colsum, float* __restrict__ rowsumQ,
    float* __restrict__ rowsumK)
{
    const int bh     = blockIdx.x / (L / ROWS_PER_BLOCK);
    const int rowblk = blockIdx.x % (L / ROWS_PER_BLOCK);
    const int wave   = threadIdx.x >> 6;
    const int lane   = threadIdx.x & 63;

    const size_t tile_base = (size_t)bh * L * DK;

    float4 cacc[4];
    #pragma unroll
    for (int i = 0; i < 4; ++i) cacc[i] = make_float4(0.f, 0.f, 0.f, 0.f);

    for (int j = 0; j < ROWS_PER_BLOCK / 4; ++j) {
        const int row = rowblk * ROWS_PER_BLOCK + wave + 4 * j;
        const size_t rbase = tile_base + (size_t)row * DK;
        float rq = 0.f, rk = 0.f;
        #pragma unroll
        for (int i = 0; i < 4; ++i) {
            const int c = i * 256 + lane * 4;
            const float4 q = *(const float4*)(Q + rbase + c);
            const float4 k = *(const float4*)(K + rbase + c);
            const float q0 = elup(q.x), q1 = elup(q.y), q2 = elup(q.z), q3 = elup(q.w);
            const float k0 = elup(k.x), k1 = elup(k.y), k2 = elup(k.z), k3 = elup(k.w);
            rq += (q0 + q1) + (q2 + q3);
            rk += (k0 + k1) + (k2 + k3);
            cacc[i].x += k0; cacc[i].y += k1; cacc[i].z += k2; cacc[i].w += k3;
        }
        // wave-level reduce (64 lanes)
        #pragma unroll
        for (int m = 32; m >= 1; m >>= 1) {
            rq += __shfl_xor(rq, m, 64);
            rk += __shfl_xor(rk, m, 64);
        }
        if (lane == 0) {
            rowsumQ[bh * L + row] = rq;
            rowsumK[bh * L + row] = rk;
        }
    }

    // Cross-wave column reduce: each wave dumps its 1024 partials to its own
    // LDS slice (float4 stores -> conflict-free), then 256 threads fold the
    // 4 slices and atomicAdd into the global per-(b,h) colsum (L2-resident).
    __shared__ float scol[4 * DK];
    #pragma unroll
    for (int i = 0; i < 4; ++i) {
        *(float4*)&scol[wave * DK + i * 256 + lane * 4] = cacc[i];
    }
    __syncthreads();
    for (int t = threadIdx.x; t < DK; t += 256) {
        const float s = scol[t] + scol[DK + t] + scol[2 * DK + t] + scol[3 * DK + t];
        atomicAdd(&colsum[bh * DK + t], s);
    }
}

// Pass 2: out = V * (rq*rk)/(rq*cs + EPS). float4 per thread.
// colsum is indexed by l (k==l in this problem), so flat index == row.
__global__ __launch_bounds__(256) void finalize_kernel(
    const float* __restrict__ V, const float* __restrict__ colsum,
    const float* __restrict__ rowsumQ, const float* __restrict__ rowsumK,
    float* __restrict__ out)
{
    const int e4  = blockIdx.x * 256 + threadIdx.x; // group of 4 elems
    const int row = e4 >> 4;                        // DV/4 = 16 groups/row
    const float rq = rowsumQ[row];
    const float rk = rowsumK[row];
    const float cs = colsum[row];
    const float scale = rq * rk / (rq * cs + EPS);
    const float4 v = *(const float4*)(V + (size_t)e4 * 4);
    float4 o;
    o.x = v.x * scale; o.y = v.y * scale; o.z = v.z * scale; o.w = v.w * scale;
    *(float4*)(out + (size_t)e4 * 4) = o;
}

extern "C" void kernel_launch(void* const* d_in, const int* in_sizes, int n_in,
                              void* d_out, int out_size, void* d_ws, size_t ws_size,
                              hipStream_t stream) {
    const float* Q = (const float*)d_in[0];
    const float* K = (const float*)d_in[1];
    const float* V = (const float*)d_in[2];
    float* out = (float*)d_out;

    float* colsum  = (float*)d_ws;        // 64*1024 f32 = 256 KB
    float* rowsumQ = colsum + NBH * L;    // 256 KB
    float* rowsumK = rowsumQ + NBH * L;   // 256 KB

    hipMemsetAsync(colsum, 0, (size_t)NBH * DK * sizeof(float), stream);

    reduce_kernel<<<NBH * (L / ROWS_PER_BLOCK), 256, 0, stream>>>(
        Q, K, colsum, rowsumQ, rowsumK);

    finalize_kernel<<<(NBH * L * DV / 4) / 256, 256, 0, stream>>>(
        V, colsum, rowsumQ, rowsumK, out);
}